// Round 1
// baseline (447.565 us; speedup 1.0000x reference)
//
#include <hip/hip_runtime.h>
#include <hip/hip_bf16.h>

// CRF loss via scaled-forward-algorithm reformulation:
//   logZ = log( (E_0 * E_1 * ... * E_511)[START][END] ), E_t = exp(M_t) elementwise
// K1: 2048 independent chunk-product chains (one wave each), 16 matrices/chunk,
//     bf16 MFMA 16x16x32, fixed 2^-7 rescale per multiply (exact, constant logscale).
// K2: per-batch sequential combine over 32 chunk matrices + target_score gather.
// K3: mean over 64 batch losses.

#define B_N 64
#define S_N 512
#define T_N 48
#define TT_N 2304              // 48*48
#define START_TAG 46
#define END_TAG 47
#define CHUNK_L 16             // matrices per chunk
#define CPB 32                 // chunks per batch (512/16)
#define N_CHUNKS 2048          // 64*32
#define RS 56                  // LDS row stride in bf16 elems (pad 48->56, 112B rows, 16B aligned)
#define LN2F 0.69314718055994530942f

typedef __bf16 bf16x8 __attribute__((ext_vector_type(8)));
typedef float f32x4 __attribute__((ext_vector_type(4)));

// ---------------- K1: chunk products ----------------
// grid 512 blocks x 256 threads; each wave = one chunk chain (4 chains/block).
// P_new = P * E_t :  A = P (state, LDS round-trip), B = E_t (global->regs, exp'd).
// K padded 48->64: pad handled purely by zeroed fragment registers (quad>=2 @ kb=1).
__global__ __launch_bounds__(256, 2) void crf_k1(const float* __restrict__ tr,
                                                 float* __restrict__ wsP) {
  const int w = threadIdx.x >> 6;
  const int lane = threadIdx.x & 63;
  const int col = lane & 15;
  const int quad = lane >> 4;
  const int g = blockIdx.x * 4 + w;      // global chunk id, 0..2047
  const int b = g >> 5;                  // batch
  const int c = g & 31;                  // chunk within batch
  const float* base = tr + ((size_t)(b * S_N + c * CHUNK_L) * TT_N);

  __shared__ __align__(16) __bf16 Pb[4][T_N * RS + 16];  // +16: pad for discarded OOB b128 read
  __bf16* __restrict__ P = &Pb[w][0];

  float st[2][3][8];  // staged raw E_t values (prefetch buffer)

  auto issue = [&](const float* tb) {
#pragma unroll
    for (int kb = 0; kb < 2; ++kb)
#pragma unroll
      for (int nt = 0; nt < 3; ++nt)
#pragma unroll
        for (int j = 0; j < 8; ++j) {
          const int k = kb * 32 + quad * 8 + j;           // B row (k dim)
          st[kb][nt][j] = (kb == 0 || quad < 2) ? tb[k * T_N + nt * 16 + col] : 0.f;
        }
  };

  bf16x8 bfr[2][3];  // B fragments of E_t
  auto convert = [&]() {
#pragma unroll
    for (int kb = 0; kb < 2; ++kb)
#pragma unroll
      for (int nt = 0; nt < 3; ++nt)
#pragma unroll
        for (int j = 0; j < 8; ++j) {
          const float e = (kb == 0 || quad < 2) ? __expf(st[kb][nt][j]) : 0.f;
          bfr[kb][nt][j] = (__bf16)e;
        }
  };

  // ---- t = 0:  C = I * E_0 ----
  issue(base);
  bf16x8 aI[3][2];
#pragma unroll
  for (int mt = 0; mt < 3; ++mt)
#pragma unroll
    for (int kb = 0; kb < 2; ++kb)
#pragma unroll
      for (int j = 0; j < 8; ++j) {
        const int k = kb * 32 + quad * 8 + j;
        aI[mt][kb][j] = (k == mt * 16 + col) ? (__bf16)1.0f : (__bf16)0.0f;
      }
  convert();
  issue(base + TT_N);  // prefetch tile 1

  f32x4 acc[3][3];
#pragma unroll
  for (int mt = 0; mt < 3; ++mt)
#pragma unroll
    for (int nt = 0; nt < 3; ++nt) {
#pragma unroll
      for (int r = 0; r < 4; ++r) acc[mt][nt][r] = 0.f;
      acc[mt][nt] = __builtin_amdgcn_mfma_f32_16x16x32_bf16(aI[mt][0], bfr[0][nt], acc[mt][nt], 0, 0, 0);
      acc[mt][nt] = __builtin_amdgcn_mfma_f32_16x16x32_bf16(aI[mt][1], bfr[1][nt], acc[mt][nt], 0, 0, 0);
    }
#pragma unroll
  for (int mt = 0; mt < 3; ++mt)
#pragma unroll
    for (int nt = 0; nt < 3; ++nt)
#pragma unroll
      for (int r = 0; r < 4; ++r) {
        const int row = mt * 16 + quad * 4 + r;           // C/D layout: row=quad*4+reg, col=lane&15
        P[row * RS + nt * 16 + col] = (__bf16)(acc[mt][nt][r] * 0.0078125f);  // 2^-7 rescale
      }

  // ---- t = 1..15 ----
  for (int t = 1; t < CHUNK_L; ++t) {
    convert();                                            // B frags for tile t
    if (t < CHUNK_L - 1) issue(base + (size_t)(t + 1) * TT_N);

    bf16x8 a[3][2];                                       // A frags of P from LDS
#pragma unroll
    for (int mt = 0; mt < 3; ++mt) {
#pragma unroll
      for (int kb = 0; kb < 2; ++kb) {
        const int off = (mt * 16 + col) * RS + kb * 32 + quad * 8;  // A[m=lane&15][k=quad*8+j]
        a[mt][kb] = *(const bf16x8*)(P + off);
      }
      if (quad >= 2) {                                    // k>=48 of padded K: force zero
#pragma unroll
        for (int j = 0; j < 8; ++j) a[mt][1][j] = (__bf16)0.0f;
      }
    }

#pragma unroll
    for (int mt = 0; mt < 3; ++mt)
#pragma unroll
      for (int nt = 0; nt < 3; ++nt) {
#pragma unroll
        for (int r = 0; r < 4; ++r) acc[mt][nt][r] = 0.f;
        acc[mt][nt] = __builtin_amdgcn_mfma_f32_16x16x32_bf16(a[mt][0], bfr[0][nt], acc[mt][nt], 0, 0, 0);
        acc[mt][nt] = __builtin_amdgcn_mfma_f32_16x16x32_bf16(a[mt][1], bfr[1][nt], acc[mt][nt], 0, 0, 0);
      }

    if (t < CHUNK_L - 1) {
#pragma unroll
      for (int mt = 0; mt < 3; ++mt)
#pragma unroll
        for (int nt = 0; nt < 3; ++nt)
#pragma unroll
          for (int r = 0; r < 4; ++r) {
            const int row = mt * 16 + quad * 4 + r;
            P[row * RS + nt * 16 + col] = (__bf16)(acc[mt][nt][r] * 0.0078125f);
          }
    }
  }

  // final product of this chunk -> ws, fp32 (carries exact scale 2^(-7*15))
  float* out = wsP + (size_t)g * TT_N;
#pragma unroll
  for (int mt = 0; mt < 3; ++mt)
#pragma unroll
    for (int nt = 0; nt < 3; ++nt)
#pragma unroll
      for (int r = 0; r < 4; ++r) {
        const int row = mt * 16 + quad * 4 + r;
        out[row * T_N + nt * 16 + col] = acc[mt][nt][r];
      }
}

// ---------------- K2: per-batch combine + target score ----------------
// 64 blocks x 64 threads (1 wave). v starts as row START of chunk-0 product,
// then v <- v * P_c sequentially with max-normalization; plus target_score gather.
__global__ __launch_bounds__(64) void crf_k2(const float* __restrict__ tr,
                                             const int* __restrict__ tgt,
                                             const float* __restrict__ wsP,
                                             float* __restrict__ wsLoss) {
  const int b = blockIdx.x;
  const int lane = threadIdx.x;
  __shared__ __align__(16) float Pl[TT_N + 64];  // +64: pad for lanes 48..63 junk reads
  __shared__ __align__(16) float vb[T_N];

  const float* c0 = wsP + (size_t)(b * CPB) * TT_N;
  float v = (lane < T_N) ? c0[START_TAG * T_N + lane] : 0.f;
  float lsc = 0.f;

  for (int c = 1; c < CPB; ++c) {
    const float4* pc = (const float4*)(wsP + (size_t)(b * CPB + c) * TT_N);
#pragma unroll
    for (int q = 0; q < 9; ++q)
      ((float4*)Pl)[q * 64 + lane] = pc[q * 64 + lane];
    if (lane < T_N) vb[lane] = v;
    __syncthreads();

    float vn = 0.f;
#pragma unroll
    for (int i = 0; i < T_N; i += 4) {
      const float4 vv = *(const float4*)&vb[i];
      vn += vv.x * Pl[(i + 0) * T_N + lane];
      vn += vv.y * Pl[(i + 1) * T_N + lane];
      vn += vv.z * Pl[(i + 2) * T_N + lane];
      vn += vv.w * Pl[(i + 3) * T_N + lane];
    }
    if (lane >= T_N) vn = 0.f;
    float m = vn;
#pragma unroll
    for (int s = 1; s < 64; s <<= 1) m = fmaxf(m, __shfl_xor(m, s));
    v = vn / m;          // all values positive; m > 0
    lsc += logf(m);
    __syncthreads();
  }

  const float v_end = __shfl(v, END_TAG);
  // constant scale: 32 chunks * 15 multiplies * 7 bits, each stored as *2^-7
  const float logZ = logf(v_end) + lsc + (float)(CPB * (CHUNK_L - 1) * 7) * LN2F;

  // target score: sum_s transition[b, s, prev_s, tgt_s]
  float ts = 0.f;
#pragma unroll
  for (int s = lane; s < S_N; s += 64) {
    const int tg = tgt[b * S_N + s];
    const int pv = (s == 0) ? START_TAG : tgt[b * S_N + s - 1];
    ts += tr[(size_t)(b * S_N + s) * TT_N + pv * T_N + tg];
  }
#pragma unroll
  for (int s = 1; s < 64; s <<= 1) ts += __shfl_xor(ts, s);

  if (lane == 0) wsLoss[b] = -ts + logZ;
}

// ---------------- K3: mean ----------------
__global__ void crf_k3(const float* __restrict__ wsLoss, float* __restrict__ out) {
  float x = wsLoss[threadIdx.x];
#pragma unroll
  for (int s = 1; s < 64; s <<= 1) x += __shfl_xor(x, s);
  if (threadIdx.x == 0) out[0] = x * (1.0f / 64.0f);
}

extern "C" void kernel_launch(void* const* d_in, const int* in_sizes, int n_in,
                              void* d_out, int out_size, void* d_ws, size_t ws_size,
                              hipStream_t stream) {
  const float* tr = (const float*)d_in[0];
  const int* tgt = (const int*)d_in[1];
  float* wsP = (float*)d_ws;                         // 2048 * 2304 fp32 = 18.9 MB
  float* wsLoss = wsP + (size_t)N_CHUNKS * TT_N;     // + 64 fp32

  crf_k1<<<N_CHUNKS / 4, 256, 0, stream>>>(tr, wsP);
  crf_k2<<<B_N, 64, 0, stream>>>(tr, tgt, wsP, wsLoss);
  crf_k3<<<1, 64, 0, stream>>>(wsLoss, (float*)d_out);
}

// Round 2
// 410.993 us; speedup vs baseline: 1.0890x; 1.0890x over previous
//
#include <hip/hip_runtime.h>
#include <hip/hip_bf16.h>

// CRF loss, round 2.
// logZ = log((E_0 * ... * E_511)[START][END]), E_t = exp(M_t) elementwise.
// K1: 2048 chunk chains (1 wave each, 16 matrices). State = transposed running
//     product held as MFMA *B*-fragments in registers; N <- E_t^T * N via
//     16x16x16 bf16 MFMA. Key identity: D layout (row=quad*4+r, col=lane&15)
//     == B layout (k=quad*4+j, n=lane&15)  -> D feeds next B, no LDS.
//     Fixed 2^-7 rescale/multiply (exact). Chunk result H = G^T * 2^-105 -> ws (bf16).
// K2: 1 block (4 waves) per batch: each wave folds 8 H's (7 multiplies, x32 each),
//     then wave0 combines the 4 wave-results (3 multiplies via LDS).
//     logZ = log(v) + (32*105 - 31*5)*ln2.
// K3: mean.

#define B_N 64
#define S_N 512
#define T_N 48
#define TT_N 2304
#define START_TAG 46
#define END_TAG 47
#define CHUNK_L 16
#define CPB 32
#define N_CHUNKS 2048
#define LN2F 0.6931471805599453f

typedef __bf16 bf16x4 __attribute__((ext_vector_type(4)));
typedef short short4v __attribute__((ext_vector_type(4)));
typedef float f32x4 __attribute__((ext_vector_type(4)));

static __device__ __forceinline__ f32x4 mfma16(bf16x4 a, bf16x4 b, f32x4 c) {
#if __has_builtin(__builtin_amdgcn_mfma_f32_16x16x16bf16_1k)
  return __builtin_amdgcn_mfma_f32_16x16x16bf16_1k(
      __builtin_bit_cast(short4v, a), __builtin_bit_cast(short4v, b), c, 0, 0, 0);
#else
  f32x4 d;
  asm("v_mfma_f32_16x16x16_bf16 %0, %1, %2, %3"
      : "=v"(d) : "v"(a), "v"(b), "v"(c));
  return d;
#endif
}

// ---------------- K1 ----------------
__global__ __launch_bounds__(256, 2) void crf_k1(const float* __restrict__ tr,
                                                 __bf16* __restrict__ wsH) {
  const int w = threadIdx.x >> 6, lane = threadIdx.x & 63;
  const int col = lane & 15, quad = lane >> 4;
  const int g = blockIdx.x * 4 + w;                 // chunk id; covers s = g*16 .. g*16+15
  const float* __restrict__ base = tr + (size_t)g * (CHUNK_L * TT_N);

  // init state: N_0 = E_0^T as B-frags.  B[k][n] = E_0[n][k] -> float4 (contiguous k)
  bf16x4 bfr[3][3];                                 // [kb][nt]
#pragma unroll
  for (int kb = 0; kb < 3; ++kb)
#pragma unroll
    for (int nt = 0; nt < 3; ++nt) {
      const float4 v = *(const float4*)(base + (size_t)((nt * 16 + col) * T_N + kb * 16 + quad * 4));
      bfr[kb][nt][0] = (__bf16)__expf(v.x);
      bfr[kb][nt][1] = (__bf16)__expf(v.y);
      bfr[kb][nt][2] = (__bf16)__expf(v.z);
      bfr[kb][nt][3] = (__bf16)__expf(v.w);
    }

  // prefetch raw E_1 in A-layout: A[m][k] = E[k][m]
  float st[3][3][4];                                // [mt][kt][j]
  {
    const float* nb = base + TT_N;
#pragma unroll
    for (int mt = 0; mt < 3; ++mt)
#pragma unroll
      for (int kt = 0; kt < 3; ++kt)
#pragma unroll
        for (int j = 0; j < 4; ++j)
          st[mt][kt][j] = nb[(kt * 16 + quad * 4 + j) * T_N + mt * 16 + col];
  }

  f32x4 acc[3][3];
  for (int t = 1; t < CHUNK_L; ++t) {
    bf16x4 a[3][3];
#pragma unroll
    for (int mt = 0; mt < 3; ++mt)
#pragma unroll
      for (int kt = 0; kt < 3; ++kt)
#pragma unroll
        for (int j = 0; j < 4; ++j)
          a[mt][kt][j] = (__bf16)__expf(st[mt][kt][j]);

    if (t < CHUNK_L - 1) {
      const float* nb = base + (size_t)(t + 1) * TT_N;
#pragma unroll
      for (int mt = 0; mt < 3; ++mt)
#pragma unroll
        for (int kt = 0; kt < 3; ++kt)
#pragma unroll
          for (int j = 0; j < 4; ++j)
            st[mt][kt][j] = nb[(kt * 16 + quad * 4 + j) * T_N + mt * 16 + col];
    }

#pragma unroll
    for (int mt = 0; mt < 3; ++mt)
#pragma unroll
      for (int nt = 0; nt < 3; ++nt) {
        f32x4 c = {0.f, 0.f, 0.f, 0.f};
        c = mfma16(a[mt][0], bfr[0][nt], c);
        c = mfma16(a[mt][1], bfr[1][nt], c);
        c = mfma16(a[mt][2], bfr[2][nt], c);
        acc[mt][nt] = c;
      }
    // D -> next B (row index becomes k index), exact 2^-7 rescale
#pragma unroll
    for (int mt = 0; mt < 3; ++mt)
#pragma unroll
      for (int nt = 0; nt < 3; ++nt)
#pragma unroll
        for (int r = 0; r < 4; ++r)
          bfr[mt][nt][r] = (__bf16)(acc[mt][nt][r] * 0.0078125f);
  }

  // store H = G^T * 2^-105, row-major [k][n], bf16
  __bf16* out = wsH + (size_t)g * TT_N;
#pragma unroll
  for (int kb = 0; kb < 3; ++kb)
#pragma unroll
    for (int nt = 0; nt < 3; ++nt)
#pragma unroll
      for (int j = 0; j < 4; ++j)
        out[(kb * 16 + quad * 4 + j) * T_N + nt * 16 + col] = bfr[kb][nt][j];
}

// ---------------- K2 ----------------
#define LDS_RS 52
__global__ __launch_bounds__(256, 2) void crf_k2(const float* __restrict__ tr,
                                                 const int* __restrict__ tgt,
                                                 const __bf16* __restrict__ wsH,
                                                 float* __restrict__ wsLoss) {
  const int b = blockIdx.x;
  const int tid = threadIdx.x;
  const int w = tid >> 6, lane = tid & 63;
  const int col = lane & 15, quad = lane >> 4;

  __shared__ __align__(16) __bf16 Sl[3][T_N * LDS_RS];
  __shared__ float red[4];

  // ---- target score (all 4 waves) ----
  float ts = 0.f;
  for (int s = tid; s < S_N; s += 256) {
    const int tg = tgt[b * S_N + s];
    const int pv = (s == 0) ? START_TAG : tgt[b * S_N + s - 1];
    ts += tr[(size_t)(b * S_N + s) * TT_N + pv * T_N + tg];
  }
#pragma unroll
  for (int s2 = 1; s2 < 64; s2 <<= 1) ts += __shfl_xor(ts, s2);
  if (lane == 0) red[w] = ts;

  // ---- wave-level product of 8 chunk matrices: S_w = (G_{8w}..G_{8w+7})^T * scale ----
  const __bf16* hb = wsH + (size_t)(b * CPB + w * 8) * TT_N;
  bf16x4 bfr[3][3];                                 // state as B-frags, init = H_{first}
#pragma unroll
  for (int kb = 0; kb < 3; ++kb)
#pragma unroll
    for (int nt = 0; nt < 3; ++nt)
#pragma unroll
      for (int j = 0; j < 4; ++j)
        bfr[kb][nt][j] = hb[(kb * 16 + quad * 4 + j) * T_N + nt * 16 + col];

  f32x4 acc[3][3];
  for (int c = 1; c < 8; ++c) {
    const __bf16* hc = hb + (size_t)c * TT_N;
    bf16x4 a[3][3];                                 // A = H_c (row-major, contiguous k)
#pragma unroll
    for (int mt = 0; mt < 3; ++mt)
#pragma unroll
      for (int kt = 0; kt < 3; ++kt)
        a[mt][kt] = *(const bf16x4*)(hc + (mt * 16 + col) * T_N + kt * 16 + quad * 4);
#pragma unroll
    for (int mt = 0; mt < 3; ++mt)
#pragma unroll
      for (int nt = 0; nt < 3; ++nt) {
        f32x4 c4 = {0.f, 0.f, 0.f, 0.f};
        c4 = mfma16(a[mt][0], bfr[0][nt], c4);
        c4 = mfma16(a[mt][1], bfr[1][nt], c4);
        c4 = mfma16(a[mt][2], bfr[2][nt], c4);
        acc[mt][nt] = c4;
      }
#pragma unroll
    for (int mt = 0; mt < 3; ++mt)
#pragma unroll
      for (int nt = 0; nt < 3; ++nt)
#pragma unroll
        for (int r = 0; r < 4; ++r)
          bfr[mt][nt][r] = (__bf16)(acc[mt][nt][r] * 32.0f);   // 2^5 per multiply
  }

  // waves 1..3 publish S_w to LDS (row-major, stride 52)
  if (w > 0) {
    __bf16* dst = &Sl[w - 1][0];
#pragma unroll
    for (int kb = 0; kb < 3; ++kb)
#pragma unroll
      for (int nt = 0; nt < 3; ++nt)
#pragma unroll
        for (int j = 0; j < 4; ++j)
          dst[(kb * 16 + quad * 4 + j) * LDS_RS + nt * 16 + col] = bfr[kb][nt][j];
  }
  __syncthreads();

  // ---- wave 0: T^T = S_3 * S_2 * S_1 * S_0 ----
  if (w == 0) {
    for (int m = 0; m < 3; ++m) {
      const __bf16* src = &Sl[m][0];
      bf16x4 a[3][3];
#pragma unroll
      for (int mt = 0; mt < 3; ++mt)
#pragma unroll
        for (int kt = 0; kt < 3; ++kt)
          a[mt][kt] = *(const bf16x4*)(src + (mt * 16 + col) * LDS_RS + kt * 16 + quad * 4);
#pragma unroll
      for (int mt = 0; mt < 3; ++mt)
#pragma unroll
        for (int nt = 0; nt < 3; ++nt) {
          f32x4 c4 = {0.f, 0.f, 0.f, 0.f};
          c4 = mfma16(a[mt][0], bfr[0][nt], c4);
          c4 = mfma16(a[mt][1], bfr[1][nt], c4);
          c4 = mfma16(a[mt][2], bfr[2][nt], c4);
          acc[mt][nt] = c4;
        }
#pragma unroll
      for (int mt = 0; mt < 3; ++mt)
#pragma unroll
        for (int nt = 0; nt < 3; ++nt)
#pragma unroll
          for (int r = 0; r < 4; ++r)
            bfr[mt][nt][r] = (__bf16)(acc[mt][nt][r] * 32.0f);
    }
    // T[START][END] = T^T[47][46] -> frag (2,2), local row 15 (quad=3,r=3), col 14 -> lane 62
    const float vv = __shfl(acc[2][2][3] * 32.0f, 62);
    if (lane == 0) {
      const float tsum = red[0] + red[1] + red[2] + red[3];
      // scale bookkeeping: 32 chunks * 2^-105, 31 K2-multiplies * 2^+5
      const float logZ = logf(vv) + (float)(CPB * 105 - 31 * 5) * LN2F;
      wsLoss[b] = -tsum + logZ;
    }
  }
}

// ---------------- K3 ----------------
__global__ void crf_k3(const float* __restrict__ wsLoss, float* __restrict__ out) {
  float x = wsLoss[threadIdx.x];
#pragma unroll
  for (int s = 1; s < 64; s <<= 1) x += __shfl_xor(x, s);
  if (threadIdx.x == 0) out[0] = x * (1.0f / 64.0f);
}

extern "C" void kernel_launch(void* const* d_in, const int* in_sizes, int n_in,
                              void* d_out, int out_size, void* d_ws, size_t ws_size,
                              hipStream_t stream) {
  const float* tr = (const float*)d_in[0];
  const int* tgt = (const int*)d_in[1];
  __bf16* wsH = (__bf16*)d_ws;                              // 2048 * 2304 bf16 = 9.4 MB
  float* wsLoss = (float*)((char*)d_ws + (size_t)N_CHUNKS * TT_N * sizeof(__bf16));

  crf_k1<<<N_CHUNKS / 4, 256, 0, stream>>>(tr, wsH);
  crf_k2<<<B_N, 256, 0, stream>>>(tr, tgt, wsH, wsLoss);
  crf_k3<<<1, 64, 0, stream>>>(wsLoss, (float*)d_out);
}